// Round 9
// baseline (406.747 us; speedup 1.0000x reference)
//
#include <hip/hip_runtime.h>
#include <math.h>

#define N0 200000
#define N1 50000
#define N2 10000
#define E0 750000
#define E1 150000
#define D 256
#define OUT 64
#define CAP 64

#define BM 128
#define BN 128
#define BKK 64

typedef unsigned int uint32;
using short8 = __attribute__((ext_vector_type(8))) short;
using f32x4 = __attribute__((ext_vector_type(4))) float;

// ---- bf16 split helpers: value v ~ bf16(hi) + bf16(lo), packed (hi<<16)|lo ----
__device__ __forceinline__ unsigned short bf16_rne(float f) {
    unsigned int u = __float_as_uint(f);
    unsigned int r = (u + 0x7FFFu + ((u >> 16) & 1u)) >> 16;
    return (unsigned short)r;
}
__device__ __forceinline__ float bf16_f32(unsigned short h) {
    return __uint_as_float(((unsigned int)h) << 16);
}
__device__ __forceinline__ uint32 pack2(float v) {
    unsigned short hi = bf16_rne(v);
    unsigned short lo = bf16_rne(v - bf16_f32(hi));
    return (((uint32)hi) << 16) | (uint32)lo;
}
__device__ __forceinline__ float unpack_f32(uint32 u) {
    return __uint_as_float(u & 0xFFFF0000u) + __uint_as_float(u << 16);
}

// ---------------------------------------------------------------------------
// Build per-target edge lists (capacity CAP per target; max degree ~38).
// ---------------------------------------------------------------------------
__global__ void fill_edges(const int* __restrict__ src, const int* __restrict__ dst,
                           int* __restrict__ cnt, int* __restrict__ eidx, int E) {
    int e = blockIdx.x * blockDim.x + threadIdx.x;
    if (e >= E) return;
    int d = dst[e];
    int pos = atomicAdd(&cnt[d], 1);
    if (pos < CAP) eidx[d * CAP + pos] = src[e];
}

// ---------------------------------------------------------------------------
// Mean-aggregate neighbor rows; output packed hi/lo bf16 (u32 per element).
// One wave per target, 64 lanes x 4 elems = 256.
// Round-7 diagnosis: VGPR=20, 0.3 outstanding loads/wave -> serialization on
// the dependent el[j] index loads. Fix: load ALL <=64 indices in ONE vector
// load (one per lane), broadcast via __shfl (register-only), and run a
// masked chunk-of-4 loop with unconditional clamped loads + 0/1-weight FMA
// accumulate so the compiler keeps ~8 row-gathers in flight per wave.
// ---------------------------------------------------------------------------
template<bool SRCPACKED>
__global__ void aggregate_p(const void* __restrict__ src, const int* __restrict__ cnt,
                            const int* __restrict__ eidx, uint32* __restrict__ aggp, int T) {
    int wave = threadIdx.x >> 6;
    int lane = threadIdx.x & 63;
    int t = blockIdx.x * 4 + wave;
    if (t >= T) return;
    int deg = cnt[t];
    int n = deg < CAP ? deg : CAP;
    int vidx = eidx[(size_t)t * CAP + lane];   // all slots, one load (garbage beyond n: masked)
    float a0 = 0.f, a1 = 0.f, a2 = 0.f, a3 = 0.f;

    for (int j0 = 0; j0 < n; j0 += 4) {
        int   s[4];
        float w[4];
        #pragma unroll
        for (int jj = 0; jj < 4; ++jj) {
            int j = j0 + jj;
            int sv = __shfl(vidx, j);
            bool act = j < n;
            s[jj] = act ? sv : 0;       // clamp: safe row 0
            w[jj] = act ? 1.f : 0.f;    // exact mask
        }
        if constexpr (SRCPACKED) {
            const uint32* sp = (const uint32*)src;
            uint4 u[4];
            #pragma unroll
            for (int jj = 0; jj < 4; ++jj)
                u[jj] = *reinterpret_cast<const uint4*>(sp + (size_t)s[jj] * D + lane * 4);
            #pragma unroll
            for (int jj = 0; jj < 4; ++jj) {
                a0 += w[jj] * unpack_f32(u[jj].x);
                a1 += w[jj] * unpack_f32(u[jj].y);
                a2 += w[jj] * unpack_f32(u[jj].z);
                a3 += w[jj] * unpack_f32(u[jj].w);
            }
        } else {
            const float* sp = (const float*)src;
            float4 v[4];
            #pragma unroll
            for (int jj = 0; jj < 4; ++jj)
                v[jj] = *reinterpret_cast<const float4*>(sp + (size_t)s[jj] * D + lane * 4);
            #pragma unroll
            for (int jj = 0; jj < 4; ++jj) {
                a0 += w[jj] * v[jj].x;
                a1 += w[jj] * v[jj].y;
                a2 += w[jj] * v[jj].z;
                a3 += w[jj] * v[jj].w;
            }
        }
    }

    float sc = deg > 0 ? 1.0f / (float)deg : 0.0f;
    uint4 o;
    o.x = pack2(a0 * sc); o.y = pack2(a1 * sc);
    o.z = pack2(a2 * sc); o.w = pack2(a3 * sc);
    *reinterpret_cast<uint4*>(aggp + (size_t)t * D + lane * 4) = o;
}

// ---------------------------------------------------------------------------
// Pack W into transposed split form: WTp[n][kc] (kc<256 -> Wl[kc][n], else Wr).
// grid 256 blocks (n), 512 threads (kc).
// ---------------------------------------------------------------------------
__global__ void pack_wt(const float* __restrict__ Wl, const float* __restrict__ Wr,
                        uint32* __restrict__ WTp) {
    int n = blockIdx.x;
    int kc = threadIdx.x;
    float v = (kc < 256) ? Wl[(size_t)kc * D + n] : Wr[(size_t)(kc - 256) * D + n];
    WTp[(size_t)n * 512 + kc] = pack2(v);
}

// ---------------------------------------------------------------------------
// Split-bf16 MFMA GEMM: C[M][256] = act([A1|A2] @ Wcat + bias), K=512.
// 3-term Markidis split per product: hi*hi + hi*lo + lo*hi (fp32 accum).
// 128x128 tile, BK=64, 4 waves (2x2), 4x4 x (16x16x32) fragments per wave.
// LDS XOR-swizzle (byte ^= (row&7)<<4) for conflict-free ds_read_b128.
// ACT 0: relu, store packed u32. ACT 1: tanh, store fp32.
// ---------------------------------------------------------------------------
template<int ACT, bool A2PACKED>
__global__ void __launch_bounds__(256, 2)
gemm_split(const uint32* __restrict__ A1p, const uint32* __restrict__ A2p,
           const float* __restrict__ A2f, const uint32* __restrict__ WTp,
           const float* __restrict__ bias, uint32* __restrict__ Cp,
           float* __restrict__ Cf, int M) {
    __shared__ char sAhi[BM * BKK * 2];
    __shared__ char sAlo[BM * BKK * 2];
    __shared__ char sBhi[BN * BKK * 2];
    __shared__ char sBlo[BN * BKK * 2];

    const int tid = threadIdx.x;
    const int m0 = blockIdx.x * BM;
    const int n0 = blockIdx.y * BN;
    const int wid = tid >> 6, lane = tid & 63;
    const int wm = wid >> 1, wn = wid & 1;
    const int lr = lane & 15;
    const int lk2 = (lane >> 4) * 16;   // byte offset of this lane's k-slice

    f32x4 acc[4][4];
    #pragma unroll
    for (int i = 0; i < 4; ++i)
        #pragma unroll
        for (int j = 0; j < 4; ++j)
            acc[i][j] = (f32x4){0.f, 0.f, 0.f, 0.f};

    for (int k0 = 0; k0 < 512; k0 += BKK) {
        if (k0) __syncthreads();
        // ---- stage A tile: 128 rows x 64 k (source u32/f32), hi/lo bf16 to LDS ----
        #pragma unroll
        for (int it = 0; it < 8; ++it) {
            int flat = it * 1024 + tid * 4;
            int row = flat >> 6;
            int kq = flat & 63;
            int m = m0 + row;
            unsigned short h0, h1, h2, h3, l0, l1, l2, l3;
            if (k0 < 256) {
                uint4 u = make_uint4(0u, 0u, 0u, 0u);
                if (m < M) u = *reinterpret_cast<const uint4*>(A1p + (size_t)m * D + k0 + kq);
                h0 = u.x >> 16; l0 = u.x & 0xffff;
                h1 = u.y >> 16; l1 = u.y & 0xffff;
                h2 = u.z >> 16; l2 = u.z & 0xffff;
                h3 = u.w >> 16; l3 = u.w & 0xffff;
            } else if constexpr (A2PACKED) {
                uint4 u = make_uint4(0u, 0u, 0u, 0u);
                if (m < M) u = *reinterpret_cast<const uint4*>(A2p + (size_t)m * D + (k0 - 256) + kq);
                h0 = u.x >> 16; l0 = u.x & 0xffff;
                h1 = u.y >> 16; l1 = u.y & 0xffff;
                h2 = u.z >> 16; l2 = u.z & 0xffff;
                h3 = u.w >> 16; l3 = u.w & 0xffff;
            } else {
                float4 f = make_float4(0.f, 0.f, 0.f, 0.f);
                if (m < M) f = *reinterpret_cast<const float4*>(A2f + (size_t)m * D + (k0 - 256) + kq);
                h0 = bf16_rne(f.x); l0 = bf16_rne(f.x - bf16_f32(h0));
                h1 = bf16_rne(f.y); l1 = bf16_rne(f.y - bf16_f32(h1));
                h2 = bf16_rne(f.z); l2 = bf16_rne(f.z - bf16_f32(h2));
                h3 = bf16_rne(f.w); l3 = bf16_rne(f.w - bf16_f32(h3));
            }
            int ba = row * (BKK * 2) + ((kq * 2) ^ ((row & 7) << 4));
            *reinterpret_cast<ushort4*>(sAhi + ba) = make_ushort4(h0, h1, h2, h3);
            *reinterpret_cast<ushort4*>(sAlo + ba) = make_ushort4(l0, l1, l2, l3);
        }
        // ---- stage B tile: 128 n-rows x 64 k from WTp (always packed) ----
        #pragma unroll
        for (int it = 0; it < 8; ++it) {
            int flat = it * 1024 + tid * 4;
            int row = flat >> 6;
            int kq = flat & 63;
            uint4 u = *reinterpret_cast<const uint4*>(WTp + (size_t)(n0 + row) * 512 + k0 + kq);
            int bb = row * (BKK * 2) + ((kq * 2) ^ ((row & 7) << 4));
            *reinterpret_cast<ushort4*>(sBhi + bb) =
                make_ushort4(u.x >> 16, u.y >> 16, u.z >> 16, u.w >> 16);
            *reinterpret_cast<ushort4*>(sBlo + bb) =
                make_ushort4(u.x & 0xffff, u.y & 0xffff, u.z & 0xffff, u.w & 0xffff);
        }
        __syncthreads();
        // ---- compute: 2 kk-slabs of K=32 ----
        #pragma unroll
        for (int kk2 = 0; kk2 < BKK * 2; kk2 += 64) {
            short8 ah[4], al[4], bh[4], bl[4];
            #pragma unroll
            for (int f = 0; f < 4; ++f) {
                int ra = wm * 64 + f * 16 + lr;
                int oa = ra * (BKK * 2) + (((kk2 + lk2)) ^ ((ra & 7) << 4));
                ah[f] = *reinterpret_cast<const short8*>(sAhi + oa);
                al[f] = *reinterpret_cast<const short8*>(sAlo + oa);
                int rb = wn * 64 + f * 16 + lr;
                int ob = rb * (BKK * 2) + (((kk2 + lk2)) ^ ((rb & 7) << 4));
                bh[f] = *reinterpret_cast<const short8*>(sBhi + ob);
                bl[f] = *reinterpret_cast<const short8*>(sBlo + ob);
            }
            #pragma unroll
            for (int i = 0; i < 4; ++i)
                #pragma unroll
                for (int j = 0; j < 4; ++j) {
                    acc[i][j] = __builtin_amdgcn_mfma_f32_16x16x32_bf16(ah[i], bh[j], acc[i][j], 0, 0, 0);
                    acc[i][j] = __builtin_amdgcn_mfma_f32_16x16x32_bf16(ah[i], bl[j], acc[i][j], 0, 0, 0);
                    acc[i][j] = __builtin_amdgcn_mfma_f32_16x16x32_bf16(al[i], bh[j], acc[i][j], 0, 0, 0);
                }
        }
    }
    // ---- epilogue: D[row][col], col = lane&15, row = (lane>>4)*4 + reg ----
    #pragma unroll
    for (int fn = 0; fn < 4; ++fn) {
        int col = n0 + wn * 64 + fn * 16 + lr;
        float bv = bias[col];
        #pragma unroll
        for (int fm = 0; fm < 4; ++fm) {
            int rbase = m0 + wm * 64 + fm * 16 + (lane >> 4) * 4;
            #pragma unroll
            for (int r = 0; r < 4; ++r) {
                int m = rbase + r;
                if (m < M) {
                    float v = acc[fm][fn][r] + bv;
                    if (ACT == 0) {
                        v = fmaxf(v, 0.f);
                        Cp[(size_t)m * D + col] = pack2(v);
                    } else {
                        Cf[(size_t)m * D + col] = tanhf(v);
                    }
                }
            }
        }
    }
}

// ---------------------------------------------------------------------------
// Final: out[M][64] = softmax(H @ Wlin + blin).
// One wave per row, NO LDS: Wlin (64 KB) is L2-resident; direct global reads.
// ---------------------------------------------------------------------------
__global__ void final_softmax(const float* __restrict__ H, const float* __restrict__ Wlin,
                              const float* __restrict__ blin, float* __restrict__ out,
                              int M) {
    int wave = threadIdx.x >> 6;
    int lane = threadIdx.x & 63;
    int r = blockIdx.x * 4 + wave;
    if (r >= M) return;

    float4 h = *reinterpret_cast<const float4*>(H + (size_t)r * D + lane * 4);
    float acc = blin[lane];
    #pragma unroll 8
    for (int kq = 0; kq < 64; ++kq) {
        float hx = __shfl(h.x, kq);
        float hy = __shfl(h.y, kq);
        float hz = __shfl(h.z, kq);
        float hw = __shfl(h.w, kq);
        acc += hx * Wlin[(4 * kq + 0) * OUT + lane];
        acc += hy * Wlin[(4 * kq + 1) * OUT + lane];
        acc += hz * Wlin[(4 * kq + 2) * OUT + lane];
        acc += hw * Wlin[(4 * kq + 3) * OUT + lane];
    }
    float mx = acc;
    #pragma unroll
    for (int off = 32; off > 0; off >>= 1) mx = fmaxf(mx, __shfl_xor(mx, off));
    float e = __expf(acc - mx);
    float s = e;
    #pragma unroll
    for (int off = 32; off > 0; off >>= 1) s += __shfl_xor(s, off);
    out[(size_t)r * OUT + lane] = e / s;
}

extern "C" void kernel_launch(void* const* d_in, const int* in_sizes, int n_in,
                              void* d_out, int out_size, void* d_ws, size_t ws_size,
                              hipStream_t stream) {
    const float* x    = (const float*)d_in[0];
    const int*   src0 = (const int*)d_in[1];
    const int*   dst0 = (const int*)d_in[2];
    const int*   src1 = (const int*)d_in[3];
    const int*   dst1 = (const int*)d_in[4];
    const float* Wl0  = (const float*)d_in[5];
    const float* bl0  = (const float*)d_in[6];
    const float* Wr0  = (const float*)d_in[7];
    const float* Wl1  = (const float*)d_in[8];
    const float* bl1  = (const float*)d_in[9];
    const float* Wr1  = (const float*)d_in[10];
    const float* Wlin = (const float*)d_in[11];
    const float* blin = (const float*)d_in[12];

    char* ws = (char*)d_ws;
    size_t off = 0;
    auto alloc = [&](size_t bytes) {
        void* p = ws + off;
        off += (bytes + 255) & ~(size_t)255;
        return p;
    };
    int*    cnt0  = (int*)alloc((size_t)N1 * 4);
    int*    eidx0 = (int*)alloc((size_t)N1 * CAP * 4);
    int*    cnt1  = (int*)alloc((size_t)N2 * 4);
    int*    eidx1 = (int*)alloc((size_t)N2 * CAP * 4);
    uint32* agg0p = (uint32*)alloc((size_t)N1 * D * 4);
    uint32* h0p   = (uint32*)alloc((size_t)N1 * D * 4);
    uint32* agg1p = (uint32*)alloc((size_t)N2 * D * 4);
    float*  h1f   = (float*)alloc((size_t)N2 * D * 4);
    uint32* WTp0  = (uint32*)alloc((size_t)D * 512 * 4);
    uint32* WTp1  = (uint32*)alloc((size_t)D * 512 * 4);

    hipMemsetAsync(cnt0, 0, (size_t)N1 * 4, stream);
    hipMemsetAsync(cnt1, 0, (size_t)N2 * 4, stream);

    pack_wt<<<256, 512, 0, stream>>>(Wl0, Wr0, WTp0);
    pack_wt<<<256, 512, 0, stream>>>(Wl1, Wr1, WTp1);

    fill_edges<<<(E0 + 255) / 256, 256, 0, stream>>>(src0, dst0, cnt0, eidx0, E0);
    aggregate_p<false><<<(N1 + 3) / 4, 256, 0, stream>>>(x, cnt0, eidx0, agg0p, N1);
    gemm_split<0, false><<<dim3((N1 + BM - 1) / BM, 2), 256, 0, stream>>>(
        agg0p, (const uint32*)nullptr, x, WTp0, bl0, h0p, (float*)nullptr, N1);

    fill_edges<<<(E1 + 255) / 256, 256, 0, stream>>>(src1, dst1, cnt1, eidx1, E1);
    aggregate_p<true><<<(N2 + 3) / 4, 256, 0, stream>>>(h0p, cnt1, eidx1, agg1p, N2);
    gemm_split<1, true><<<dim3((N2 + BM - 1) / BM, 2), 256, 0, stream>>>(
        agg1p, h0p, (const float*)nullptr, WTp1, bl1, (uint32*)nullptr, h1f, N2);

    final_softmax<<<(N2 + 3) / 4, 256, 0, stream>>>(h1f, Wlin, blin, (float*)d_out, N2);
}

// Round 10
// 374.774 us; speedup vs baseline: 1.0853x; 1.0853x over previous
//
#include <hip/hip_runtime.h>
#include <math.h>

#define N0 200000
#define N1 50000
#define N2 10000
#define E0 750000
#define E1 150000
#define D 256
#define OUT 64
#define CAP 64

#define BM 128
#define BN 128
// K-step = 64 elems (128 B per LDS row)

typedef unsigned int uint32;
using short8 = __attribute__((ext_vector_type(8))) short;
using f32x4 = __attribute__((ext_vector_type(4))) float;

// ---- bf16 split helpers: v ~ bf16(hi) + bf16(lo) ----
__device__ __forceinline__ unsigned short bf16_rne(float f) {
    unsigned int u = __float_as_uint(f);
    unsigned int r = (u + 0x7FFFu + ((u >> 16) & 1u)) >> 16;
    return (unsigned short)r;
}
__device__ __forceinline__ float bf16_f32(unsigned short h) {
    return __uint_as_float(((unsigned int)h) << 16);
}

// direct global->LDS copy, 16B per lane. LDS dest = wave-uniform base + lane*16.
__device__ __forceinline__ void gload_lds16(const void* g, void* l) {
    __builtin_amdgcn_global_load_lds(
        (const __attribute__((address_space(1))) unsigned int*)g,
        (__attribute__((address_space(3))) unsigned int*)l, 16, 0, 0);
}

// ---------------------------------------------------------------------------
// Build per-target edge lists (capacity CAP per target; max degree ~38).
// ---------------------------------------------------------------------------
__global__ void fill_edges(const int* __restrict__ src, const int* __restrict__ dst,
                           int* __restrict__ cnt, int* __restrict__ eidx, int E) {
    int e = blockIdx.x * blockDim.x + threadIdx.x;
    if (e >= E) return;
    int d = dst[e];
    int pos = atomicAdd(&cnt[d], 1);
    if (pos < CAP) eidx[d * CAP + pos] = src[e];
}

// ---------------------------------------------------------------------------
// Split fp32 -> (hi bf16, lo bf16) planes. 4 elems/thread.
// ---------------------------------------------------------------------------
__global__ void split_f32(const float* __restrict__ in, unsigned short* __restrict__ hi,
                          unsigned short* __restrict__ lo, int n4) {
    int i = blockIdx.x * blockDim.x + threadIdx.x;
    if (i >= n4) return;
    float4 v = *reinterpret_cast<const float4*>(in + (size_t)i * 4);
    ushort4 h, l;
    h.x = bf16_rne(v.x); l.x = bf16_rne(v.x - bf16_f32(h.x));
    h.y = bf16_rne(v.y); l.y = bf16_rne(v.y - bf16_f32(h.y));
    h.z = bf16_rne(v.z); l.z = bf16_rne(v.z - bf16_f32(h.z));
    h.w = bf16_rne(v.w); l.w = bf16_rne(v.w - bf16_f32(h.w));
    *reinterpret_cast<ushort4*>(hi + (size_t)i * 4) = h;
    *reinterpret_cast<ushort4*>(lo + (size_t)i * 4) = l;
}

// ---------------------------------------------------------------------------
// Pack W transposed+split: WThi/WTlo[n][kc] (kc<256 -> Wl[kc][n], else Wr).
// ---------------------------------------------------------------------------
__global__ void pack_wt(const float* __restrict__ Wl, const float* __restrict__ Wr,
                        unsigned short* __restrict__ WThi, unsigned short* __restrict__ WTlo) {
    int n = blockIdx.x;
    int kc = threadIdx.x;
    float v = (kc < 256) ? Wl[(size_t)kc * D + n] : Wr[(size_t)(kc - 256) * D + n];
    unsigned short h = bf16_rne(v);
    WThi[(size_t)n * 512 + kc] = h;
    WTlo[(size_t)n * 512 + kc] = bf16_rne(v - bf16_f32(h));
}

// ---------------------------------------------------------------------------
// Mean-aggregate neighbor rows -> split hi/lo bf16 planes.
// SRCMODE 0: srcA = fp32 [n][256]. SRCMODE 1: srcA/srcB = hi/lo bf16 planes.
// One wave per target; masked chunk-of-4 gather (round-9 structure; at the
// gather fabric ceiling ~5.7 TB/s effective, m13-per-CU limited).
// ---------------------------------------------------------------------------
template<int SRCMODE>
__global__ void aggregate_s(const void* __restrict__ srcA, const void* __restrict__ srcB,
                            const int* __restrict__ cnt, const int* __restrict__ eidx,
                            unsigned short* __restrict__ aggHi, unsigned short* __restrict__ aggLo,
                            int T) {
    int wave = threadIdx.x >> 6;
    int lane = threadIdx.x & 63;
    int t = blockIdx.x * 4 + wave;
    if (t >= T) return;
    int deg = cnt[t];
    int n = deg < CAP ? deg : CAP;
    int vidx = eidx[(size_t)t * CAP + lane];
    float a0 = 0.f, a1 = 0.f, a2 = 0.f, a3 = 0.f;

    for (int j0 = 0; j0 < n; j0 += 4) {
        int   s[4];
        float w[4];
        #pragma unroll
        for (int jj = 0; jj < 4; ++jj) {
            int j = j0 + jj;
            int sv = __shfl(vidx, j);
            bool act = j < n;
            s[jj] = act ? sv : 0;
            w[jj] = act ? 1.f : 0.f;
        }
        if constexpr (SRCMODE == 0) {
            const float* sp = (const float*)srcA;
            float4 v[4];
            #pragma unroll
            for (int jj = 0; jj < 4; ++jj)
                v[jj] = *reinterpret_cast<const float4*>(sp + (size_t)s[jj] * D + lane * 4);
            #pragma unroll
            for (int jj = 0; jj < 4; ++jj) {
                a0 += w[jj] * v[jj].x; a1 += w[jj] * v[jj].y;
                a2 += w[jj] * v[jj].z; a3 += w[jj] * v[jj].w;
            }
        } else {
            const unsigned short* sh = (const unsigned short*)srcA;
            const unsigned short* sl = (const unsigned short*)srcB;
            ushort4 uh[4], ul[4];
            #pragma unroll
            for (int jj = 0; jj < 4; ++jj) {
                uh[jj] = *reinterpret_cast<const ushort4*>(sh + (size_t)s[jj] * D + lane * 4);
                ul[jj] = *reinterpret_cast<const ushort4*>(sl + (size_t)s[jj] * D + lane * 4);
            }
            #pragma unroll
            for (int jj = 0; jj < 4; ++jj) {
                a0 += w[jj] * (bf16_f32(uh[jj].x) + bf16_f32(ul[jj].x));
                a1 += w[jj] * (bf16_f32(uh[jj].y) + bf16_f32(ul[jj].y));
                a2 += w[jj] * (bf16_f32(uh[jj].z) + bf16_f32(ul[jj].z));
                a3 += w[jj] * (bf16_f32(uh[jj].w) + bf16_f32(ul[jj].w));
            }
        }
    }

    float sc = deg > 0 ? 1.0f / (float)deg : 0.0f;
    a0 *= sc; a1 *= sc; a2 *= sc; a3 *= sc;
    ushort4 oh, ol;
    oh.x = bf16_rne(a0); ol.x = bf16_rne(a0 - bf16_f32(oh.x));
    oh.y = bf16_rne(a1); ol.y = bf16_rne(a1 - bf16_f32(oh.y));
    oh.z = bf16_rne(a2); ol.z = bf16_rne(a2 - bf16_f32(oh.z));
    oh.w = bf16_rne(a3); ol.w = bf16_rne(a3 - bf16_f32(oh.w));
    *reinterpret_cast<ushort4*>(aggHi + (size_t)t * D + lane * 4) = oh;
    *reinterpret_cast<ushort4*>(aggLo + (size_t)t * D + lane * 4) = ol;
}

// ---------------------------------------------------------------------------
// Split-bf16 MFMA GEMM: C[M][256] = act([A1|A2] @ Wcat + bias), K=512.
// All operands pre-split hi/lo bf16 planes. Staging = global_load_lds w16
// with pre-swizzled SOURCE (linear LDS dest); read side keeps the verified
// XOR addressing (byte ^= (row&7)<<4) -> 2-way bank aliasing (free, m136).
// 3-term Markidis accumulate; 4 waves 2x2; 4x4 16x16x32 fragments per wave.
// ACT 0: relu -> split-plane store. ACT 1: tanh -> fp32 store.
// ---------------------------------------------------------------------------
template<int ACT>
__global__ void __launch_bounds__(256, 2)
gemm_split(const unsigned short* __restrict__ A1hi, const unsigned short* __restrict__ A1lo,
           const unsigned short* __restrict__ A2hi, const unsigned short* __restrict__ A2lo,
           const unsigned short* __restrict__ WThi, const unsigned short* __restrict__ WTlo,
           const float* __restrict__ bias, unsigned short* __restrict__ Chi,
           unsigned short* __restrict__ Clo, float* __restrict__ Cf, int M) {
    __shared__ __align__(16) char sAhi[BM * 128];
    __shared__ __align__(16) char sAlo[BM * 128];
    __shared__ __align__(16) char sBhi[BN * 128];
    __shared__ __align__(16) char sBlo[BN * 128];

    const int tid = threadIdx.x;
    const int m0 = blockIdx.x * BM;
    const int n0 = blockIdx.y * BN;
    const int wid = tid >> 6, lane = tid & 63;
    const int wm = wid >> 1, wn = wid & 1;
    const int lr = lane & 15;
    const int hi2 = lane >> 4;

    // staging geometry: each wave-inst covers 8 rows x 128B; lane -> (row, col)
    const int srow = lane >> 3;                    // row within 8-row chunk
    const int scol = ((lane & 7) ^ srow) << 4;     // pre-swizzled source byte col

    f32x4 acc[4][4];
    #pragma unroll
    for (int i = 0; i < 4; ++i)
        #pragma unroll
        for (int j = 0; j < 4; ++j)
            acc[i][j] = (f32x4){0.f, 0.f, 0.f, 0.f};

    for (int k0 = 0; k0 < 512; k0 += 64) {
        if (k0) __syncthreads();
        const char* Ah = (const char*)((k0 < 256) ? A1hi : A2hi);
        const char* Al = (const char*)((k0 < 256) ? A1lo : A2lo);
        const int kc = k0 & 255;
        #pragma unroll
        for (int i = 0; i < 4; ++i) {
            int ch = wid * 4 + i;                  // 8-row chunk index (wave-uniform)
            int row = ch * 8 + srow;
            size_t ga = ((size_t)(m0 + row) * D + kc) * 2 + scol;
            size_t gb = ((size_t)(n0 + row) * 512 + k0) * 2 + scol;
            gload_lds16(Ah + ga, sAhi + ch * 1024);
            gload_lds16(Al + ga, sAlo + ch * 1024);
            gload_lds16((const char*)WThi + gb, sBhi + ch * 1024);
            gload_lds16((const char*)WTlo + gb, sBlo + ch * 1024);
        }
        __syncthreads();   // compiler drains vmcnt(0) before barrier -> LDS ready

        #pragma unroll
        for (int slab = 0; slab < 2; ++slab) {
            const int z = slab * 64 + hi2 * 16;
            short8 ah[4], al[4], bh[4], bl[4];
            #pragma unroll
            for (int f = 0; f < 4; ++f) {
                int ra = wm * 64 + f * 16 + lr;
                int oa = ra * 128 + (z ^ ((ra & 7) << 4));
                ah[f] = *reinterpret_cast<const short8*>(sAhi + oa);
                al[f] = *reinterpret_cast<const short8*>(sAlo + oa);
                int rb = wn * 64 + f * 16 + lr;
                int ob = rb * 128 + (z ^ ((rb & 7) << 4));
                bh[f] = *reinterpret_cast<const short8*>(sBhi + ob);
                bl[f] = *reinterpret_cast<const short8*>(sBlo + ob);
            }
            #pragma unroll
            for (int i = 0; i < 4; ++i)
                #pragma unroll
                for (int j = 0; j < 4; ++j) {
                    acc[i][j] = __builtin_amdgcn_mfma_f32_16x16x32_bf16(ah[i], bh[j], acc[i][j], 0, 0, 0);
                    acc[i][j] = __builtin_amdgcn_mfma_f32_16x16x32_bf16(ah[i], bl[j], acc[i][j], 0, 0, 0);
                    acc[i][j] = __builtin_amdgcn_mfma_f32_16x16x32_bf16(al[i], bh[j], acc[i][j], 0, 0, 0);
                }
        }
    }

    // epilogue: D[row][col], col = lane&15, row = (lane>>4)*4 + reg
    #pragma unroll
    for (int fn = 0; fn < 4; ++fn) {
        int col = n0 + wn * 64 + fn * 16 + lr;
        float bv = bias[col];
        #pragma unroll
        for (int fm = 0; fm < 4; ++fm) {
            int rbase = m0 + wm * 64 + fm * 16 + hi2 * 4;
            #pragma unroll
            for (int r = 0; r < 4; ++r) {
                int m = rbase + r;
                if (m < M) {
                    float v = acc[fm][fn][r] + bv;
                    if (ACT == 0) {
                        v = fmaxf(v, 0.f);
                        unsigned short h = bf16_rne(v);
                        Chi[(size_t)m * D + col] = h;
                        Clo[(size_t)m * D + col] = bf16_rne(v - bf16_f32(h));
                    } else {
                        Cf[(size_t)m * D + col] = tanhf(v);
                    }
                }
            }
        }
    }
}

// ---------------------------------------------------------------------------
// Final: out[M][64] = softmax(H @ Wlin + blin). One wave/row, no LDS.
// ---------------------------------------------------------------------------
__global__ void final_softmax(const float* __restrict__ H, const float* __restrict__ Wlin,
                              const float* __restrict__ blin, float* __restrict__ out,
                              int M) {
    int wave = threadIdx.x >> 6;
    int lane = threadIdx.x & 63;
    int r = blockIdx.x * 4 + wave;
    if (r >= M) return;

    float4 h = *reinterpret_cast<const float4*>(H + (size_t)r * D + lane * 4);
    float acc = blin[lane];
    #pragma unroll 8
    for (int kq = 0; kq < 64; ++kq) {
        float hx = __shfl(h.x, kq);
        float hy = __shfl(h.y, kq);
        float hz = __shfl(h.z, kq);
        float hw = __shfl(h.w, kq);
        acc += hx * Wlin[(4 * kq + 0) * OUT + lane];
        acc += hy * Wlin[(4 * kq + 1) * OUT + lane];
        acc += hz * Wlin[(4 * kq + 2) * OUT + lane];
        acc += hw * Wlin[(4 * kq + 3) * OUT + lane];
    }
    float mx = acc;
    #pragma unroll
    for (int off = 32; off > 0; off >>= 1) mx = fmaxf(mx, __shfl_xor(mx, off));
    float e = __expf(acc - mx);
    float s = e;
    #pragma unroll
    for (int off = 32; off > 0; off >>= 1) s += __shfl_xor(s, off);
    out[(size_t)r * OUT + lane] = e / s;
}

extern "C" void kernel_launch(void* const* d_in, const int* in_sizes, int n_in,
                              void* d_out, int out_size, void* d_ws, size_t ws_size,
                              hipStream_t stream) {
    const float* x    = (const float*)d_in[0];
    const int*   src0 = (const int*)d_in[1];
    const int*   dst0 = (const int*)d_in[2];
    const int*   src1 = (const int*)d_in[3];
    const int*   dst1 = (const int*)d_in[4];
    const float* Wl0  = (const float*)d_in[5];
    const float* bl0  = (const float*)d_in[6];
    const float* Wr0  = (const float*)d_in[7];
    const float* Wl1  = (const float*)d_in[8];
    const float* bl1  = (const float*)d_in[9];
    const float* Wr1  = (const float*)d_in[10];
    const float* Wlin = (const float*)d_in[11];
    const float* blin = (const float*)d_in[12];

    const int PAD1 = 50048;   // 391*128  (gload_lds reads unmasked -> pad rows)
    const int PAD2 = 10112;   // 79*128

    char* ws = (char*)d_ws;
    size_t off = 0;
    auto alloc = [&](size_t bytes) {
        void* p = ws + off;
        off += (bytes + 255) & ~(size_t)255;
        return p;
    };
    int* cnt0  = (int*)alloc((size_t)N1 * 4);
    int* eidx0 = (int*)alloc((size_t)N1 * CAP * 4);
    int* cnt1  = (int*)alloc((size_t)N2 * 4);
    int* eidx1 = (int*)alloc((size_t)N2 * CAP * 4);
    unsigned short* agg0hi = (unsigned short*)alloc((size_t)PAD1 * D * 2);
    unsigned short* agg0lo = (unsigned short*)alloc((size_t)PAD1 * D * 2);
    unsigned short* xhi    = (unsigned short*)alloc((size_t)PAD1 * D * 2);
    unsigned short* xlo    = (unsigned short*)alloc((size_t)PAD1 * D * 2);
    unsigned short* h0hi   = (unsigned short*)alloc((size_t)N1 * D * 2);
    unsigned short* h0lo   = (unsigned short*)alloc((size_t)N1 * D * 2);
    unsigned short* agg1hi = (unsigned short*)alloc((size_t)PAD2 * D * 2);
    unsigned short* agg1lo = (unsigned short*)alloc((size_t)PAD2 * D * 2);
    float* h1f = (float*)alloc((size_t)N2 * D * 4);
    unsigned short* WThi0 = (unsigned short*)alloc((size_t)D * 512 * 2);
    unsigned short* WTlo0 = (unsigned short*)alloc((size_t)D * 512 * 2);
    unsigned short* WThi1 = (unsigned short*)alloc((size_t)D * 512 * 2);
    unsigned short* WTlo1 = (unsigned short*)alloc((size_t)D * 512 * 2);

    hipMemsetAsync(cnt0, 0, (size_t)N1 * 4, stream);
    hipMemsetAsync(cnt1, 0, (size_t)N2 * 4, stream);

    split_f32<<<(N1 * D / 4 + 255) / 256, 256, 0, stream>>>(x, xhi, xlo, N1 * D / 4);
    pack_wt<<<256, 512, 0, stream>>>(Wl0, Wr0, WThi0, WTlo0);
    pack_wt<<<256, 512, 0, stream>>>(Wl1, Wr1, WThi1, WTlo1);

    fill_edges<<<(E0 + 255) / 256, 256, 0, stream>>>(src0, dst0, cnt0, eidx0, E0);
    aggregate_s<0><<<(N1 + 3) / 4, 256, 0, stream>>>(x, nullptr, cnt0, eidx0, agg0hi, agg0lo, N1);
    gemm_split<0><<<dim3((N1 + BM - 1) / BM, 2), 256, 0, stream>>>(
        agg0hi, agg0lo, xhi, xlo, WThi0, WTlo0, bl0, h0hi, h0lo, (float*)nullptr, N1);

    fill_edges<<<(E1 + 255) / 256, 256, 0, stream>>>(src1, dst1, cnt1, eidx1, E1);
    aggregate_s<1><<<(N2 + 3) / 4, 256, 0, stream>>>(h0hi, h0lo, cnt1, eidx1, agg1hi, agg1lo, N2);
    gemm_split<1><<<dim3((N2 + BM - 1) / BM, 2), 256, 0, stream>>>(
        agg1hi, agg1lo, h0hi, h0lo, WThi1, WTlo1, bl1,
        (unsigned short*)nullptr, (unsigned short*)nullptr, h1f, N2);

    final_softmax<<<(N2 + 3) / 4, 256, 0, stream>>>(h1f, Wlin, blin, (float*)d_out, N2);
}

// Round 11
// 362.979 us; speedup vs baseline: 1.1206x; 1.0325x over previous
//
#include <hip/hip_runtime.h>
#include <math.h>

#define N0 200000
#define N1 50000
#define N2 10000
#define E0 750000
#define E1 150000
#define D 256
#define OUT 64
#define CAP 64

#define BM 64
#define BN 128
#define FS_ROWS 32

typedef unsigned int uint32;
using short8 = __attribute__((ext_vector_type(8))) short;
using f32x4 = __attribute__((ext_vector_type(4))) float;

// ---- bf16 split helpers: v ~ bf16(hi) + bf16(lo) ----
__device__ __forceinline__ unsigned short bf16_rne(float f) {
    unsigned int u = __float_as_uint(f);
    unsigned int r = (u + 0x7FFFu + ((u >> 16) & 1u)) >> 16;
    return (unsigned short)r;
}
__device__ __forceinline__ float bf16_f32(unsigned short h) {
    return __uint_as_float(((unsigned int)h) << 16);
}

// direct global->LDS copy, 16B per lane. LDS dest = wave-uniform base + lane*16.
__device__ __forceinline__ void gload_lds16(const void* g, void* l) {
    __builtin_amdgcn_global_load_lds(
        (const __attribute__((address_space(1))) unsigned int*)g,
        (__attribute__((address_space(3))) unsigned int*)l, 16, 0, 0);
}

// ---------------------------------------------------------------------------
// Build per-target edge lists (capacity CAP per target; max degree ~38).
// ---------------------------------------------------------------------------
__global__ void fill_edges(const int* __restrict__ src, const int* __restrict__ dst,
                           int* __restrict__ cnt, int* __restrict__ eidx, int E) {
    int e = blockIdx.x * blockDim.x + threadIdx.x;
    if (e >= E) return;
    int d = dst[e];
    int pos = atomicAdd(&cnt[d], 1);
    if (pos < CAP) eidx[d * CAP + pos] = src[e];
}

// ---------------------------------------------------------------------------
// Split fp32 -> (hi bf16, lo bf16) planes. 4 elems/thread.
// ---------------------------------------------------------------------------
__global__ void split_f32(const float* __restrict__ in, unsigned short* __restrict__ hi,
                          unsigned short* __restrict__ lo, int n4) {
    int i = blockIdx.x * blockDim.x + threadIdx.x;
    if (i >= n4) return;
    float4 v = *reinterpret_cast<const float4*>(in + (size_t)i * 4);
    ushort4 h, l;
    h.x = bf16_rne(v.x); l.x = bf16_rne(v.x - bf16_f32(h.x));
    h.y = bf16_rne(v.y); l.y = bf16_rne(v.y - bf16_f32(h.y));
    h.z = bf16_rne(v.z); l.z = bf16_rne(v.z - bf16_f32(h.z));
    h.w = bf16_rne(v.w); l.w = bf16_rne(v.w - bf16_f32(h.w));
    *reinterpret_cast<ushort4*>(hi + (size_t)i * 4) = h;
    *reinterpret_cast<ushort4*>(lo + (size_t)i * 4) = l;
}

// ---------------------------------------------------------------------------
// Pack W transposed+split: WThi/WTlo[n][kc] (kc<256 -> Wl[kc][n], else Wr).
// ---------------------------------------------------------------------------
__global__ void pack_wt(const float* __restrict__ Wl, const float* __restrict__ Wr,
                        unsigned short* __restrict__ WThi, unsigned short* __restrict__ WTlo) {
    int n = blockIdx.x;
    int kc = threadIdx.x;
    float v = (kc < 256) ? Wl[(size_t)kc * D + n] : Wr[(size_t)(kc - 256) * D + n];
    unsigned short h = bf16_rne(v);
    WThi[(size_t)n * 512 + kc] = h;
    WTlo[(size_t)n * 512 + kc] = bf16_rne(v - bf16_f32(h));
}

// ---------------------------------------------------------------------------
// Mean-aggregate neighbor rows -> split hi/lo bf16 planes.
// At the per-CU delivery ceiling (24.4 GB/s/CU = m13 streaming limit) — done.
// ---------------------------------------------------------------------------
template<int SRCMODE>
__global__ void aggregate_s(const void* __restrict__ srcA, const void* __restrict__ srcB,
                            const int* __restrict__ cnt, const int* __restrict__ eidx,
                            unsigned short* __restrict__ aggHi, unsigned short* __restrict__ aggLo,
                            int T) {
    int wave = threadIdx.x >> 6;
    int lane = threadIdx.x & 63;
    int t = blockIdx.x * 4 + wave;
    if (t >= T) return;
    int deg = cnt[t];
    int n = deg < CAP ? deg : CAP;
    int vidx = eidx[(size_t)t * CAP + lane];
    float a0 = 0.f, a1 = 0.f, a2 = 0.f, a3 = 0.f;

    for (int j0 = 0; j0 < n; j0 += 4) {
        int   s[4];
        float w[4];
        #pragma unroll
        for (int jj = 0; jj < 4; ++jj) {
            int j = j0 + jj;
            int sv = __shfl(vidx, j);
            bool act = j < n;
            s[jj] = act ? sv : 0;
            w[jj] = act ? 1.f : 0.f;
        }
        if constexpr (SRCMODE == 0) {
            const float* sp = (const float*)srcA;
            float4 v[4];
            #pragma unroll
            for (int jj = 0; jj < 4; ++jj)
                v[jj] = *reinterpret_cast<const float4*>(sp + (size_t)s[jj] * D + lane * 4);
            #pragma unroll
            for (int jj = 0; jj < 4; ++jj) {
                a0 += w[jj] * v[jj].x; a1 += w[jj] * v[jj].y;
                a2 += w[jj] * v[jj].z; a3 += w[jj] * v[jj].w;
            }
        } else {
            const unsigned short* sh = (const unsigned short*)srcA;
            const unsigned short* sl = (const unsigned short*)srcB;
            ushort4 uh[4], ul[4];
            #pragma unroll
            for (int jj = 0; jj < 4; ++jj) {
                uh[jj] = *reinterpret_cast<const ushort4*>(sh + (size_t)s[jj] * D + lane * 4);
                ul[jj] = *reinterpret_cast<const ushort4*>(sl + (size_t)s[jj] * D + lane * 4);
            }
            #pragma unroll
            for (int jj = 0; jj < 4; ++jj) {
                a0 += w[jj] * (bf16_f32(uh[jj].x) + bf16_f32(ul[jj].x));
                a1 += w[jj] * (bf16_f32(uh[jj].y) + bf16_f32(ul[jj].y));
                a2 += w[jj] * (bf16_f32(uh[jj].z) + bf16_f32(ul[jj].z));
                a3 += w[jj] * (bf16_f32(uh[jj].w) + bf16_f32(ul[jj].w));
            }
        }
    }

    float sc = deg > 0 ? 1.0f / (float)deg : 0.0f;
    a0 *= sc; a1 *= sc; a2 *= sc; a3 *= sc;
    ushort4 oh, ol;
    oh.x = bf16_rne(a0); ol.x = bf16_rne(a0 - bf16_f32(oh.x));
    oh.y = bf16_rne(a1); ol.y = bf16_rne(a1 - bf16_f32(oh.y));
    oh.z = bf16_rne(a2); ol.z = bf16_rne(a2 - bf16_f32(oh.z));
    oh.w = bf16_rne(a3); ol.w = bf16_rne(a3 - bf16_f32(oh.w));
    *reinterpret_cast<ushort4*>(aggHi + (size_t)t * D + lane * 4) = oh;
    *reinterpret_cast<ushort4*>(aggLo + (size_t)t * D + lane * 4) = ol;
}

// ---------------------------------------------------------------------------
// Split-bf16 MFMA GEMM, retiled 64x128 (was 128x128).
// Round-10 theory: 782 blocks @ 2/CU = 76% avg occupancy w/ 53% tail round.
// BM=64: 1564 blocks, 48 KB LDS -> 3 blocks/CU, 2.04 even rounds.
// Waves 1x4 over N; per wave 4x2 16x16 fragments. Same gload_lds w16 staging
// with pre-swizzled source + XOR read addressing (verified r4-r10).
// ---------------------------------------------------------------------------
template<int ACT>
__global__ void __launch_bounds__(256, 3)
gemm_split(const unsigned short* __restrict__ A1hi, const unsigned short* __restrict__ A1lo,
           const unsigned short* __restrict__ A2hi, const unsigned short* __restrict__ A2lo,
           const unsigned short* __restrict__ WThi, const unsigned short* __restrict__ WTlo,
           const float* __restrict__ bias, unsigned short* __restrict__ Chi,
           unsigned short* __restrict__ Clo, float* __restrict__ Cf, int M) {
    __shared__ __align__(16) char sAhi[BM * 128];   //  8 KB
    __shared__ __align__(16) char sAlo[BM * 128];   //  8 KB
    __shared__ __align__(16) char sBhi[BN * 128];   // 16 KB
    __shared__ __align__(16) char sBlo[BN * 128];   // 16 KB

    const int tid = threadIdx.x;
    const int m0 = blockIdx.x * BM;
    const int n0 = blockIdx.y * BN;
    const int wid = tid >> 6, lane = tid & 63;
    const int lr = lane & 15;
    const int hi2 = lane >> 4;

    const int srow = lane >> 3;                    // row within 8-row chunk
    const int scol = ((lane & 7) ^ srow) << 4;     // pre-swizzled source byte col

    f32x4 acc[4][2];
    #pragma unroll
    for (int i = 0; i < 4; ++i)
        #pragma unroll
        for (int j = 0; j < 2; ++j)
            acc[i][j] = (f32x4){0.f, 0.f, 0.f, 0.f};

    for (int k0 = 0; k0 < 512; k0 += 64) {
        if (k0) __syncthreads();   // prior compute done before LDS overwrite
        const char* Ah = (const char*)((k0 < 256) ? A1hi : A2hi);
        const char* Al = (const char*)((k0 < 256) ? A1lo : A2lo);
        const int kc = k0 & 255;
        // A: 8 chunks of 8 rows, 2 per wave
        #pragma unroll
        for (int i = 0; i < 2; ++i) {
            int ch = wid * 2 + i;
            int row = ch * 8 + srow;
            size_t ga = ((size_t)(m0 + row) * D + kc) * 2 + scol;
            gload_lds16(Ah + ga, sAhi + ch * 1024);
            gload_lds16(Al + ga, sAlo + ch * 1024);
        }
        // B: 16 chunks of 8 rows, 4 per wave
        #pragma unroll
        for (int i = 0; i < 4; ++i) {
            int ch = wid * 4 + i;
            int row = ch * 8 + srow;
            size_t gb = ((size_t)(n0 + row) * 512 + k0) * 2 + scol;
            gload_lds16((const char*)WThi + gb, sBhi + ch * 1024);
            gload_lds16((const char*)WTlo + gb, sBlo + ch * 1024);
        }
        __syncthreads();   // vmcnt(0) drained by compiler before barrier

        #pragma unroll
        for (int slab = 0; slab < 2; ++slab) {
            const int z = slab * 64 + hi2 * 16;
            short8 ah[4], al[4], bh[2], bl[2];
            #pragma unroll
            for (int f = 0; f < 4; ++f) {
                int ra = f * 16 + lr;
                int oa = ra * 128 + (z ^ ((ra & 7) << 4));
                ah[f] = *reinterpret_cast<const short8*>(sAhi + oa);
                al[f] = *reinterpret_cast<const short8*>(sAlo + oa);
            }
            #pragma unroll
            for (int f = 0; f < 2; ++f) {
                int rb = wid * 32 + f * 16 + lr;
                int ob = rb * 128 + (z ^ ((rb & 7) << 4));
                bh[f] = *reinterpret_cast<const short8*>(sBhi + ob);
                bl[f] = *reinterpret_cast<const short8*>(sBlo + ob);
            }
            #pragma unroll
            for (int i = 0; i < 4; ++i)
                #pragma unroll
                for (int j = 0; j < 2; ++j) {
                    acc[i][j] = __builtin_amdgcn_mfma_f32_16x16x32_bf16(ah[i], bh[j], acc[i][j], 0, 0, 0);
                    acc[i][j] = __builtin_amdgcn_mfma_f32_16x16x32_bf16(ah[i], bl[j], acc[i][j], 0, 0, 0);
                    acc[i][j] = __builtin_amdgcn_mfma_f32_16x16x32_bf16(al[i], bh[j], acc[i][j], 0, 0, 0);
                }
        }
    }

    // epilogue: D[row][col], col = lane&15, row = (lane>>4)*4 + reg
    #pragma unroll
    for (int fn = 0; fn < 2; ++fn) {
        int col = n0 + wid * 32 + fn * 16 + lr;
        float bv = bias[col];
        #pragma unroll
        for (int fm = 0; fm < 4; ++fm) {
            int rbase = m0 + fm * 16 + hi2 * 4;
            #pragma unroll
            for (int r = 0; r < 4; ++r) {
                int m = rbase + r;
                if (m < M) {
                    float v = acc[fm][fn][r] + bv;
                    if (ACT == 0) {
                        v = fmaxf(v, 0.f);
                        unsigned short h = bf16_rne(v);
                        Chi[(size_t)m * D + col] = h;
                        Clo[(size_t)m * D + col] = bf16_rne(v - bf16_f32(h));
                    } else {
                        Cf[(size_t)m * D + col] = tanhf(v);
                    }
                }
            }
        }
    }
}

// ---------------------------------------------------------------------------
// Final: out[M][64] = softmax(H @ Wlin + blin).
// v3: Wlin staged once per block in LDS (kills the 640 MB L2 re-read);
// H row via wave-uniform scalar loads (out of the dependent chain);
// 4 independent partial accumulators -> chain = fma-latency only.
// (Round-4's 252 us was the serial shfl->fma chain at 1 wave/SIMD; round-5's
// fix was occupancy; this removes the chain itself.)
// ---------------------------------------------------------------------------
__global__ void __launch_bounds__(256)
final_softmax(const float* __restrict__ H, const float* __restrict__ Wlin,
              const float* __restrict__ blin, float* __restrict__ out, int M) {
    __shared__ __align__(16) float sW[D * OUT];   // 64 KB
    const int tid = threadIdx.x;
    #pragma unroll
    for (int i = 0; i < 16; ++i) {
        int idx = (i * 256 + tid) * 4;
        *reinterpret_cast<float4*>(&sW[idx]) = *reinterpret_cast<const float4*>(&Wlin[idx]);
    }
    __syncthreads();

    const int wave = tid >> 6, lane = tid & 63;
    const float bl = blin[lane];
    int r0 = blockIdx.x * FS_ROWS + wave * (FS_ROWS / 4);
    int r1 = r0 + FS_ROWS / 4;
    for (int r = r0; r < r1 && r < M; ++r) {
        const float* hrow = H + (size_t)r * D;   // wave-uniform -> scalar loads
        float a0 = 0.f, a1 = 0.f, a2 = 0.f, a3 = 0.f;
        #pragma unroll 8
        for (int k = 0; k < D; k += 4) {
            a0 += hrow[k + 0] * sW[(k + 0) * OUT + lane];
            a1 += hrow[k + 1] * sW[(k + 1) * OUT + lane];
            a2 += hrow[k + 2] * sW[(k + 2) * OUT + lane];
            a3 += hrow[k + 3] * sW[(k + 3) * OUT + lane];
        }
        float acc = (a0 + a1) + (a2 + a3) + bl;
        float mx = acc;
        #pragma unroll
        for (int off = 32; off > 0; off >>= 1) mx = fmaxf(mx, __shfl_xor(mx, off));
        float e = __expf(acc - mx);
        float s = e;
        #pragma unroll
        for (int off = 32; off > 0; off >>= 1) s += __shfl_xor(s, off);
        out[(size_t)r * OUT + lane] = e / s;
    }
}

extern "C" void kernel_launch(void* const* d_in, const int* in_sizes, int n_in,
                              void* d_out, int out_size, void* d_ws, size_t ws_size,
                              hipStream_t stream) {
    const float* x    = (const float*)d_in[0];
    const int*   src0 = (const int*)d_in[1];
    const int*   dst0 = (const int*)d_in[2];
    const int*   src1 = (const int*)d_in[3];
    const int*   dst1 = (const int*)d_in[4];
    const float* Wl0  = (const float*)d_in[5];
    const float* bl0  = (const float*)d_in[6];
    const float* Wr0  = (const float*)d_in[7];
    const float* Wl1  = (const float*)d_in[8];
    const float* bl1  = (const float*)d_in[9];
    const float* Wr1  = (const float*)d_in[10];
    const float* Wlin = (const float*)d_in[11];
    const float* blin = (const float*)d_in[12];

    const int PAD1 = 50048;   // 782*64 (gload_lds reads unmasked -> pad rows)
    const int PAD2 = 10112;   // 158*64

    char* ws = (char*)d_ws;
    size_t off = 0;
    auto alloc = [&](size_t bytes) {
        void* p = ws + off;
        off += (bytes + 255) & ~(size_t)255;
        return p;
    };
    int* cnt0  = (int*)alloc((size_t)N1 * 4);
    int* eidx0 = (int*)alloc((size_t)N1 * CAP * 4);
    int* cnt1  = (int*)alloc((size_t)N2 * 4);
    int* eidx1 = (int*)alloc((size_t)N2 * CAP * 4);
    unsigned short* agg0hi = (unsigned short*)alloc((size_t)PAD1 * D * 2);
    unsigned short* agg0lo = (unsigned short*)alloc((size_t)PAD1 * D * 2);
    unsigned short* xhi    = (unsigned short*)alloc((size_t)PAD1 * D * 2);
    unsigned short* xlo    = (unsigned short*)alloc((size_t)PAD1 * D * 2);
    unsigned short* h0hi   = (unsigned short*)alloc((size_t)N1 * D * 2);
    unsigned short* h0lo   = (unsigned short*)alloc((size_t)N1 * D * 2);
    unsigned short* agg1hi = (unsigned short*)alloc((size_t)PAD2 * D * 2);
    unsigned short* agg1lo = (unsigned short*)alloc((size_t)PAD2 * D * 2);
    float* h1f = (float*)alloc((size_t)N2 * D * 4);
    unsigned short* WThi0 = (unsigned short*)alloc((size_t)D * 512 * 2);
    unsigned short* WTlo0 = (unsigned short*)alloc((size_t)D * 512 * 2);
    unsigned short* WThi1 = (unsigned short*)alloc((size_t)D * 512 * 2);
    unsigned short* WTlo1 = (unsigned short*)alloc((size_t)D * 512 * 2);

    hipMemsetAsync(cnt0, 0, (size_t)N1 * 4, stream);
    hipMemsetAsync(cnt1, 0, (size_t)N2 * 4, stream);

    split_f32<<<(N1 * D / 4 + 255) / 256, 256, 0, stream>>>(x, xhi, xlo, N1 * D / 4);
    pack_wt<<<256, 512, 0, stream>>>(Wl0, Wr0, WThi0, WTlo0);
    pack_wt<<<256, 512, 0, stream>>>(Wl1, Wr1, WThi1, WTlo1);

    fill_edges<<<(E0 + 255) / 256, 256, 0, stream>>>(src0, dst0, cnt0, eidx0, E0);
    aggregate_s<0><<<(N1 + 3) / 4, 256, 0, stream>>>(x, nullptr, cnt0, eidx0, agg0hi, agg0lo, N1);
    gemm_split<0><<<dim3((N1 + BM - 1) / BM, 2), 256, 0, stream>>>(
        agg0hi, agg0lo, xhi, xlo, WThi0, WTlo0, bl0, h0hi, h0lo, (float*)nullptr, N1);

    fill_edges<<<(E1 + 255) / 256, 256, 0, stream>>>(src1, dst1, cnt1, eidx1, E1);
    aggregate_s<1><<<(N2 + 3) / 4, 256, 0, stream>>>(h0hi, h0lo, cnt1, eidx1, agg1hi, agg1lo, N2);
    gemm_split<1><<<dim3((N2 + BM - 1) / BM, 2), 256, 0, stream>>>(
        agg1hi, agg1lo, h0hi, h0lo, WThi1, WTlo1, bl1,
        (unsigned short*)nullptr, (unsigned short*)nullptr, h1f, N2);

    final_softmax<<<(N2 + FS_ROWS - 1) / FS_ROWS, 256, 0, stream>>>(
        h1f, Wlin, blin, (float*)d_out, N2);
}